// Round 10
// baseline (157.516 us; speedup 1.0000x reference)
//
#include <hip/hip_runtime.h>
#include <math.h>

// Problem constants: B=32, C=D=64, H=W=32
#define NPTS 32768
#define KCB  1024
#define DIM  64
#define HW   1024
#define CHW  65536

typedef short  bf16x8 __attribute__((ext_vector_type(8)));
typedef float  f32x16 __attribute__((ext_vector_type(16)));

__device__ __forceinline__ unsigned short f2b_rne(float f) {
  unsigned u = __float_as_uint(f);
  unsigned r = 0x7FFFu + ((u >> 16) & 1u);
  return (unsigned short)((u + r) >> 16);
}

__device__ __forceinline__ float block_sum(float v, float* scratch) {
  #pragma unroll
  for (int o = 32; o > 0; o >>= 1) v += __shfl_down(v, o, 64);
  int wid = threadIdx.x >> 6, lane = threadIdx.x & 63;
  __syncthreads();
  if (lane == 0) scratch[wid] = v;
  __syncthreads();
  float s = 0.f;
  int nw = blockDim.x >> 6;
  for (int w2 = 0; w2 < nw; ++w2) s += scratch[w2];
  return s;
}

// K0: codebook -> fragment-ordered bf16 hi/lo array + cnorm (exact chain) + zero ctrl.
// cbf (f4 units): chunk ch (64 codes) at ch*1024; hi frag (nt,s) for lane (u,n) at
// (nt*4+s)*64 + u*32 + n; lo at +512. K-loop loads are lane-linear = coalesced 1 KB.
__global__ __launch_bounds__(64) void k_cvt(const float* __restrict__ cb,
                                            float4* __restrict__ cbf,
                                            float* __restrict__ cnorm,
                                            int* __restrict__ hist,
                                            int* __restrict__ done,
                                            float* __restrict__ mseacc) {
  int c = blockIdx.x * 64 + threadIdx.x;   // 16 blocks x 64 = 1024 codes
  hist[c] = 0;
  if (c == 0) { *done = 0; *mseacc = 0.f; }
  const float4* row4 = (const float4*)(cb + c * DIM);
  float4 r[16];
  #pragma unroll
  for (int i = 0; i < 16; ++i) r[i] = row4[i];
  float s = 0.f;
  #pragma unroll
  for (int i = 0; i < 16; ++i) {          // exact f4 fmaf chain (validated R3..R9)
    s = fmaf(r[i].x, r[i].x, s); s = fmaf(r[i].y, r[i].y, s);
    s = fmaf(r[i].z, r[i].z, s); s = fmaf(r[i].w, r[i].w, s);
  }
  cnorm[c] = s;
  int ch = c >> 6, nt = (c >> 5) & 1, n = c & 31;
  int base = ch * 1024 + nt * 256 + n;
  #pragma unroll
  for (int o = 0; o < 8; ++o) {           // octet o = dims 8o..8o+7
    float f[8] = {r[2*o].x, r[2*o].y, r[2*o].z, r[2*o].w,
                  r[2*o+1].x, r[2*o+1].y, r[2*o+1].z, r[2*o+1].w};
    unsigned hu[4], lu[4];
    #pragma unroll
    for (int j = 0; j < 4; ++j) {
      unsigned short h0 = f2b_rne(f[2*j]),   h1 = f2b_rne(f[2*j+1]);
      float hf0 = __uint_as_float((unsigned)h0 << 16);
      float hf1 = __uint_as_float((unsigned)h1 << 16);
      unsigned short l0 = f2b_rne(f[2*j] - hf0), l1 = f2b_rne(f[2*j+1] - hf1);
      hu[j] = (unsigned)h0 | ((unsigned)h1 << 16);
      lu[j] = (unsigned)l0 | ((unsigned)l1 << 16);
    }
    int pos = base + (o >> 1) * 64 + (o & 1) * 32;   // s = o>>1, u = o&1
    uint4 hv = {hu[0], hu[1], hu[2], hu[3]};
    uint4 lv = {lu[0], lu[1], lu[2], lu[3]};
    cbf[pos]       = *(float4*)&hv;
    cbf[pos + 512] = *(float4*)&lv;
  }
}

// K1: barrier-free streaming MFMA distance GEMM + fused fin + last-block OT.
// 1024 blocks x 128 thr (2 waves). Block owns 32 pts; wave wn streams code half
// [wn*512,+512) as 8 chunks: 16 coalesced global f4 loads -> 24 MFMAs, no LDS/no
// barriers in the loop. Last block (done-counter) runs prep+banded-OT+scalars.
__global__ __launch_bounds__(128, 2) void k_dist(const float* __restrict__ x,
                                                 const float* __restrict__ cb,
                                                 const float4* __restrict__ cbf,
                                                 const float* __restrict__ cnorm,
                                                 int* __restrict__ hist,
                                                 int* __restrict__ done,
                                                 float* __restrict__ mseacc,
                                                 float* __restrict__ out) {
  __shared__ float4 s_af[2][4][64];       // [hilo][s][lane] A-frags, 8 KB, lane-linear
  __shared__ float  lpf[64][32];          // exact f32 x tile [c][p], 8 KB
  __shared__ float  s_part[4][32];
  __shared__ float  s_sx[32];
  __shared__ unsigned long long s_pk[32][2];
  __shared__ int    s_bd[32];
  __shared__ float  scratch[2];
  __shared__ int    s_last;
  __shared__ __align__(16) float s_lt[KCB + 8], s_src[KCB + 8],
                                 s_phi[KCB + 8], s_lse[KCB + 8];

  int tid = threadIdx.x;
  int t   = blockIdx.x;
  int n0  = t * 32;
  int b   = n0 >> 10;
  int hw0 = n0 & 1023;
  int p   = tid & 31, g = tid >> 5;       // point, dim-group [16g,16g+16)

  // prologue: load+convert 32 points (bit-exact chains, R8/R9-validated pattern)
  {
    const float* xb = x + b * CHW + hw0 + p;
    float s = 0.f;
    unsigned short hb[16], lb[16];
    #pragma unroll
    for (int i = 0; i < 16; ++i) {
      int c = g * 16 + i;
      float f = xb[c * HW];               // lanes p consecutive: coalesced 128 B
      s = fmaf(f, f, s);
      lpf[c][p] = f;
      unsigned short h = f2b_rne(f);
      float hf = __uint_as_float(((unsigned)h) << 16);
      hb[i] = h;
      lb[i] = f2b_rne(f - hf);
    }
    s_part[g][p] = s;
    unsigned hu0[4], hu1[4], lu0[4], lu1[4];
    #pragma unroll
    for (int j = 0; j < 4; ++j) {
      hu0[j] = (unsigned)hb[2*j]     | ((unsigned)hb[2*j+1] << 16);
      hu1[j] = (unsigned)hb[8+2*j]   | ((unsigned)hb[8+2*j+1] << 16);
      lu0[j] = (unsigned)lb[2*j]     | ((unsigned)lb[2*j+1] << 16);
      lu1[j] = (unsigned)lb[8+2*j]   | ((unsigned)lb[8+2*j+1] << 16);
    }
    uint4 a0 = {hu0[0],hu0[1],hu0[2],hu0[3]}, a1 = {hu1[0],hu1[1],hu1[2],hu1[3]};
    uint4 c0 = {lu0[0],lu0[1],lu0[2],lu0[3]}, c1 = {lu1[0],lu1[1],lu1[2],lu1[3]};
    s_af[0][g][p]      = *(float4*)&a0;   // octet 2g   (u=0)
    s_af[0][g][32 + p] = *(float4*)&a1;   // octet 2g+1 (u=1)
    s_af[1][g][p]      = *(float4*)&c0;
    s_af[1][g][32 + p] = *(float4*)&c1;
  }
  __syncthreads();
  if (tid < 32)
    s_sx[tid] = ((s_part[0][tid] + s_part[1][tid]) + s_part[2][tid]) + s_part[3][tid];
  __syncthreads();

  int w = tid >> 6;            // wave = code half wn
  int l = tid & 63;
  int u = l >> 5, n = l & 31;

  bf16x8 ah[4], al[4];
  #pragma unroll
  for (int s4 = 0; s4 < 4; ++s4) {       // lane-linear ds_read_b128, conflict-free
    ah[s4] = *(bf16x8*)&s_af[0][s4][l];
    al[s4] = *(bf16x8*)&s_af[1][s4][l];
  }
  // C/D 32x32 layout: col=lane&31 (code), row=(r&3)+8*(r>>2)+4*u (pt)  [m74/m101]
  float sxr[16];
  #pragma unroll
  for (int r = 0; r < 16; ++r) sxr[r] = s_sx[(r & 3) + 8 * (r >> 2) + 4 * u];

  float best[16]; int bidx[16];
  #pragma unroll
  for (int r = 0; r < 16; ++r) { best[r] = 3.4e38f; bidx[r] = 0; }

  #pragma unroll 1
  for (int c8 = 0; c8 < 8; ++c8) {
    int ch = w * 8 + c8;
    const float4* bp = cbf + ch * 1024 + l;
    float4 bh[8], bl[8];                  // [nt*4+s]; 16 coalesced 1KB loads
    #pragma unroll
    for (int q2 = 0; q2 < 8; ++q2) {
      bh[q2] = bp[q2 * 64];
      bl[q2] = bp[q2 * 64 + 512];
    }
    float cn0 = cnorm[ch * 64 + n];
    float cn1 = cnorm[ch * 64 + 32 + n];
    f32x16 a0, a1;
    #pragma unroll
    for (int r = 0; r < 16; ++r) { a0[r] = 0.f; a1[r] = 0.f; }
    #pragma unroll
    for (int s4 = 0; s4 < 4; ++s4) {      // per-acc chain order == R9 (bit-exact)
      a0 = __builtin_amdgcn_mfma_f32_32x32x16_bf16(ah[s4], *(bf16x8*)&bh[s4],     a0, 0, 0, 0);
      a1 = __builtin_amdgcn_mfma_f32_32x32x16_bf16(ah[s4], *(bf16x8*)&bh[4 + s4], a1, 0, 0, 0);
      a0 = __builtin_amdgcn_mfma_f32_32x32x16_bf16(ah[s4], *(bf16x8*)&bl[s4],     a0, 0, 0, 0);
      a1 = __builtin_amdgcn_mfma_f32_32x32x16_bf16(ah[s4], *(bf16x8*)&bl[4 + s4], a1, 0, 0, 0);
      a0 = __builtin_amdgcn_mfma_f32_32x32x16_bf16(al[s4], *(bf16x8*)&bh[s4],     a0, 0, 0, 0);
      a1 = __builtin_amdgcn_mfma_f32_32x32x16_bf16(al[s4], *(bf16x8*)&bh[4 + s4], a1, 0, 0, 0);
    }
    #pragma unroll
    for (int r = 0; r < 16; ++r) {        // nt0 before nt1: k ascending -> first-min
      float d0 = (sxr[r] + cn0) - 2.0f * a0[r];
      if (d0 < best[r]) { best[r] = d0; bidx[r] = ch * 64 + n; }
      float d1 = (sxr[r] + cn1) - 2.0f * a1[r];
      if (d1 < best[r]) { best[r] = d1; bidx[r] = ch * 64 + 32 + n; }
    }
  }

  // cross-lane argmin over n (32 codes/col-group), then cross-wave via LDS
  #pragma unroll
  for (int r = 0; r < 16; ++r) {
    unsigned long long pk =
        ((unsigned long long)__float_as_uint(best[r]) << 32) | (unsigned)bidx[r];
    #pragma unroll
    for (int m = 1; m < 32; m <<= 1) {
      unsigned long long o = __shfl_xor(pk, m, 64);
      pk = (o < pk) ? o : pk;
    }
    if (n == 0) s_pk[(r & 3) + 8 * (r >> 2) + 4 * u][w] = pk;
  }
  __syncthreads();
  if (tid < 32) {
    unsigned long long a = s_pk[tid][0], c2 = s_pk[tid][1];
    unsigned long long mn = (c2 < a) ? c2 : a;   // tie -> lower idx (half0 < half1)
    int bd = (int)(mn & 0xffffffffull);
    s_bd[tid] = bd;
    atomicAdd(&hist[bd], 1);
  }
  __syncthreads();

  // fused fin: gather code row, straight-through write (ref rounding), mse
  float se = 0.f;
  {
    int bd = s_bd[p];
    const float* crow = cb + bd * DIM;
    float* op = out + b * CHW + hw0 + p;
    #pragma unroll 4
    for (int i = 0; i < 16; ++i) {
      int c = g * 16 + i;
      float xv   = lpf[c][p];            // bit-exact x copy
      float diff = crow[c] - xv;         // nq - x
      se += diff * diff;                 // (clean_q - flat)^2 == commit mse
      op[c * HW] = xv + diff;            // x + stop_grad(nq - x)
    }
  }
  float tot = block_sum(se, scratch);
  if (tid == 0) {
    atomicAdd(mseacc, tot);
    __threadfence();                     // device-scope release before counter
    int old = atomicAdd(done, 1);
    s_last = (old == 1023);
  }
  __syncthreads();
  if (!s_last) return;

  // ---------- last block: prep + banded OT dual ascent + scalars ----------
  __threadfence();                       // acquire: invalidate stale cache lines
  float msetot = *mseacc;
  int i0 = tid * 8;                      // 128 threads x 8 elems

  int4 ha = *(const int4*)(hist + i0);
  int4 hb4 = *(const int4*)(hist + i0 + 4);
  int hi[8] = {ha.x, ha.y, ha.z, ha.w, hb4.x, hb4.y, hb4.z, hb4.w};
  float tj[8], hj[8];
  #pragma unroll
  for (int j = 0; j < 8; ++j) {
    float fi = (float)(i0 + j);
    float zz = (fi - 511.5f) / (1024.0f / 6.0f);
    tj[j] = expf(-0.5f * zz * zz);
    hj[j] = (float)hi[j] * (1.0f / 32768.0f);
  }
  float l1 = 0.f;
  #pragma unroll
  for (int j = 0; j < 8; ++j) l1 += tj[j];
  float St = block_sum(l1, scratch);
  float tgt[8], ltw[8];
  float l2 = 0.f;
  #pragma unroll
  for (int j = 0; j < 8; ++j) { tgt[j] = fmaxf(tj[j] / fmaxf(St, 1e-12f), 1e-12f); l2 += tgt[j]; }
  float St2 = block_sum(l2, scratch);
  #pragma unroll
  for (int j = 0; j < 8; ++j) { tgt[j] = tgt[j] / St2; ltw[j] = logf(fmaxf(tgt[j], 1e-12f)); }

  float srcw[8];
  float l3 = 0.f;
  #pragma unroll
  for (int j = 0; j < 8; ++j) { srcw[j] = fmaxf(hj[j], 1e-12f); l3 += srcw[j]; }
  float S1 = block_sum(l3, scratch);
  float l4 = 0.f;
  #pragma unroll
  for (int j = 0; j < 8; ++j) { srcw[j] = fmaxf(srcw[j] / S1, 1e-12f); l4 += srcw[j]; }
  float S2 = block_sum(l4, scratch);
  float l5 = 0.f;
  #pragma unroll
  for (int j = 0; j < 8; ++j) { srcw[j] = srcw[j] / S2; l5 += hj[j] * logf(hj[j] + 1e-10f); }
  float ent = block_sum(l5, scratch);

  *(float4*)&s_lt[i0 + 4]  = make_float4(ltw[0], ltw[1], ltw[2], ltw[3]);
  *(float4*)&s_lt[i0 + 8]  = make_float4(ltw[4], ltw[5], ltw[6], ltw[7]);
  *(float4*)&s_src[i0 + 4] = make_float4(srcw[0], srcw[1], srcw[2], srcw[3]);
  *(float4*)&s_src[i0 + 8] = make_float4(srcw[4], srcw[5], srcw[6], srcw[7]);
  *(float4*)&s_phi[i0 + 4] = make_float4(0.f, 0.f, 0.f, 0.f);
  *(float4*)&s_phi[i0 + 8] = make_float4(0.f, 0.f, 0.f, 0.f);
  *(float4*)&s_lse[i0 + 4] = make_float4(0.f, 0.f, 0.f, 0.f);
  *(float4*)&s_lse[i0 + 8] = make_float4(0.f, 0.f, 0.f, 0.f);
  if (tid == 0) {                        // pads: inert (validated R3..R9)
    #pragma unroll
    for (int pp = 0; pp < 4; ++pp) {
      s_lt[pp] = -100.f; s_src[pp] = 0.f; s_phi[pp] = 0.f; s_lse[pp] = 0.f;
      s_lt[KCB+4+pp] = -100.f; s_src[KCB+4+pp] = 0.f;
      s_phi[KCB+4+pp] = 0.f;   s_lse[KCB+4+pp] = 0.f;
    }
  }
  __syncthreads();

  float wsr[16];
  #pragma unroll
  for (int m = 0; m < 4; ++m) *(float4*)&wsr[m*4] = *(float4*)&s_src[i0 + m*4];

  float phi[8] = {0.f,0.f,0.f,0.f,0.f,0.f,0.f,0.f};
  float lse[8];
  for (int it = 0; it <= 10; ++it) {
    float wl[16], wp[16];
    #pragma unroll
    for (int m = 0; m < 4; ++m) {
      *(float4*)&wl[m*4] = *(float4*)&s_lt[i0 + m*4];
      *(float4*)&wp[m*4] = *(float4*)&s_phi[i0 + m*4];
    }
    #pragma unroll
    for (int j = 0; j < 8; ++j) {
      float mx = -3.0e38f;
      float vv[5];
      #pragma unroll
      for (int q = 0; q < 5; ++q) {
        int m = j + q + 2;               // LDS idx offset: (i0+j-2+q)+4 - i0
        float a = wl[m] + (wp[m] - fabsf((float)(q - 2))) * 20.0f;
        vv[q] = a;
        mx = fmaxf(mx, a);
      }
      float ssum = 0.f;
      #pragma unroll
      for (int q = 0; q < 5; ++q) ssum += expf(vv[q] - mx);
      lse[j] = mx + logf(ssum);
    }
    *(float4*)&s_lse[i0 + 4] = make_float4(lse[0], lse[1], lse[2], lse[3]);
    *(float4*)&s_lse[i0 + 8] = make_float4(lse[4], lse[5], lse[6], lse[7]);
    __syncthreads();
    if (it == 10) break;

    float we[16];
    #pragma unroll
    for (int m = 0; m < 4; ++m) *(float4*)&we[m*4] = *(float4*)&s_lse[i0 + m*4];
    #pragma unroll
    for (int j = 0; j < 8; ++j) {
      float basej = ltw[j] + phi[j] * 20.0f;
      float cs = 0.f;
      #pragma unroll
      for (int q = 0; q < 5; ++q) {
        int m = j + q + 2;
        float a = basej - fabsf((float)(q - 2)) * 20.0f;
        cs += wsr[m] * expf(a - we[m]);
      }
      phi[j] += 0.5f * (tgt[j] - cs);
    }
    *(float4*)&s_phi[i0 + 4] = make_float4(phi[0], phi[1], phi[2], phi[3]);
    *(float4*)&s_phi[i0 + 8] = make_float4(phi[4], phi[5], phi[6], phi[7]);
    __syncthreads();
  }

  float lo = 0.f;
  #pragma unroll
  for (int j = 0; j < 8; ++j) lo += srcw[j] * (-0.05f * lse[j]) + tgt[j] * phi[j];
  float ot = block_sum(lo, scratch);

  if (tid == 0) {
    out[2097152] = 1.25f * (msetot * (1.0f / 2097152.0f)) + ot;
    out[2097153] = expf(-ent);
  }
}

extern "C" void kernel_launch(void* const* d_in, const int* in_sizes, int n_in,
                              void* d_out, int out_size, void* d_ws, size_t ws_size,
                              hipStream_t stream) {
  const float* x  = (const float*)d_in[0];   // [32,64,32,32]
  const float* cb = (const float*)d_in[1];   // [1024,64]
  float* out = (float*)d_out;                // quantized(2097152) | loss | perplexity

  float4* cbf   = (float4*)d_ws;                       // 256 KB fragment-ordered codes
  float*  cnorm = (float*)((char*)d_ws + 262144);      // 4 KB
  int*    hist  = (int*)((char*)d_ws + 266240);        // 4 KB
  int*    done  = (int*)((char*)d_ws + 270336);        // 4 B
  float*  mseacc= (float*)((char*)d_ws + 270400);      // 4 B

  k_cvt<<<16, 64, 0, stream>>>(cb, cbf, cnorm, hist, done, mseacc);
  k_dist<<<1024, 128, 0, stream>>>(x, cb, cbf, cnorm, hist, done, mseacc, out);
}

// Round 11
// 143.836 us; speedup vs baseline: 1.0951x; 1.0951x over previous
//
#include <hip/hip_runtime.h>
#include <math.h>

// Problem constants: B=32, C=D=64, H=W=32
#define NPTS 32768
#define KCB  1024
#define DIM  64
#define HW   1024
#define CHW  65536

typedef short  bf16x8 __attribute__((ext_vector_type(8)));
typedef float  f32x4  __attribute__((ext_vector_type(4)));

__device__ __forceinline__ unsigned short f2b_rne(float f) {
  unsigned u = __float_as_uint(f);
  unsigned r = 0x7FFFu + ((u >> 16) & 1u);
  return (unsigned short)((u + r) >> 16);
}

__device__ __forceinline__ float block_sum(float v, float* scratch) {
  #pragma unroll
  for (int o = 32; o > 0; o >>= 1) v += __shfl_down(v, o, 64);
  int wid = threadIdx.x >> 6, lane = threadIdx.x & 63;
  __syncthreads();
  if (lane == 0) scratch[wid] = v;
  __syncthreads();
  float s = 0.f;
  int nw = blockDim.x >> 6;
  for (int w2 = 0; w2 < nw; ++w2) s += scratch[w2];
  return s;
}

// K0: codebook -> fragment-ordered bf16 hi/lo array (16x16-frag order) + cnorm + zero ctrl.
// cbf (f4 units), chunk ch = 64 codes at ch*1024:
//   hi frag for (nt, kk, lane l=q*16+c16) at nt*128 + kk*64 + l ; lo at +512.
// k_dist staging is a LINEAR copy; B-frag reads are lane-linear b128 -> conflict-free.
__global__ __launch_bounds__(64) void k_cvt(const float* __restrict__ cb,
                                            float4* __restrict__ cbf,
                                            float* __restrict__ cnorm,
                                            int* __restrict__ hist,
                                            int* __restrict__ done,
                                            float* __restrict__ mseacc) {
  int c = blockIdx.x * 64 + threadIdx.x;   // 16 blocks x 64 = 1024 codes
  hist[c] = 0;
  if (c == 0) { *done = 0; *mseacc = 0.f; }
  const float4* row4 = (const float4*)(cb + c * DIM);
  float4 r[16];
  #pragma unroll
  for (int i = 0; i < 16; ++i) r[i] = row4[i];
  float s = 0.f;
  #pragma unroll
  for (int i = 0; i < 16; ++i) {          // exact f4 fmaf chain (validated R3..R10)
    s = fmaf(r[i].x, r[i].x, s); s = fmaf(r[i].y, r[i].y, s);
    s = fmaf(r[i].z, r[i].z, s); s = fmaf(r[i].w, r[i].w, s);
  }
  cnorm[c] = s;
  int ch = c >> 6, cc = c & 63, nt = cc >> 4, c16 = cc & 15;
  float fr[16][4];
  #pragma unroll
  for (int i = 0; i < 16; ++i) { fr[i][0]=r[i].x; fr[i][1]=r[i].y; fr[i][2]=r[i].z; fr[i][3]=r[i].w; }
  #pragma unroll
  for (int kk = 0; kk < 2; ++kk) {
    #pragma unroll
    for (int q = 0; q < 4; ++q) {         // f4 = dims kk*32+q*8 .. +7
      int d0 = kk * 32 + q * 8;
      unsigned hu[4], lu[4];
      #pragma unroll
      for (int j = 0; j < 4; ++j) {
        int d = d0 + 2 * j;
        float f0 = fr[d >> 2][d & 3], f1 = fr[(d+1) >> 2][(d+1) & 3];
        unsigned short h0 = f2b_rne(f0), h1 = f2b_rne(f1);
        float hf0 = __uint_as_float((unsigned)h0 << 16);
        float hf1 = __uint_as_float((unsigned)h1 << 16);
        unsigned short l0 = f2b_rne(f0 - hf0), l1 = f2b_rne(f1 - hf1);
        hu[j] = (unsigned)h0 | ((unsigned)h1 << 16);
        lu[j] = (unsigned)l0 | ((unsigned)l1 << 16);
      }
      int pos = ch * 1024 + nt * 128 + kk * 64 + q * 16 + c16;
      uint4 hv = {hu[0], hu[1], hu[2], hu[3]};
      uint4 lv = {lu[0], lu[1], lu[2], lu[3]};
      cbf[pos]       = *(float4*)&hv;
      cbf[pos + 512] = *(float4*)&lv;
    }
  }
}

// K1: R8-structure MFMA distance GEMM (proven 45us) + conflict-free cbf staging +
// lgkm-only barrier2 + fused fin + last-block OT. 512 blocks x 256 thr x 64 pts.
__global__ __launch_bounds__(256, 2) void k_dist(const float* __restrict__ x,
                                                 const float* __restrict__ cb,
                                                 const float4* __restrict__ cbf,
                                                 const float* __restrict__ cnorm,
                                                 int* __restrict__ hist,
                                                 int* __restrict__ done,
                                                 float* __restrict__ mseacc,
                                                 float* __restrict__ out) {
  __shared__ __align__(16) char sm[56864];
  short (*lph)[72]   = (short(*)[72])(sm);            //  9216 B  point bf16 hi
  short (*lpl)[72]   = (short(*)[72])(sm + 9216);     //  9216 B  point bf16 lo
  short* lcf         = (short*)(sm + 18432);          // 16384 B  code frag chunk
  float (*lpf)[64]   = (float(*)[64])(sm + 34816);    // 16384 B  exact f32 x tile
  float* s_cn        = (float*)(sm + 51200);          //  4096 B
  float (*s_part)[64]= (float(*)[64])(sm + 55296);    //  1024 B
  float* s_sx        = (float*)(sm + 56320);          //   256 B
  int*   s_bd        = (int*)(sm + 56576);            //   256 B
  float* scratch     = (float*)(sm + 56832);          //    16 B
  int*   s_last      = (int*)(sm + 56848);
  // OT-phase aliases (last block only, after all GEMM use of lph/lpl):
  float* s_lt  = (float*)(sm);
  float* s_src = (float*)(sm + 4128);
  float* s_phi = (float*)(sm + 8256);
  float* s_lse = (float*)(sm + 12384);                // ends 16512 <= 18432

  int tid = threadIdx.x;
  int t   = blockIdx.x;
  int n0  = t * 64;
  int b   = n0 >> 10;
  int hw0 = n0 & 1023;

  *(float4*)&s_cn[tid * 4] = *(const float4*)(cnorm + tid * 4);

  // point staging + bf16 hi/lo conversion (R8-validated pattern, bit-exact chains)
  {
    int p = tid & 63, q4 = tid >> 6;
    const float* xb = x + b * CHW + hw0 + p;
    float s = 0.f;
    unsigned short hb[16], lb[16];
    #pragma unroll
    for (int i = 0; i < 16; ++i) {
      int c = q4 * 16 + i;
      float f = xb[c * HW];
      s = fmaf(f, f, s);
      lpf[c][p] = f;
      unsigned short h = f2b_rne(f);
      float hf = __uint_as_float(((unsigned)h) << 16);
      hb[i] = h;
      lb[i] = f2b_rne(f - hf);
    }
    s_part[q4][p] = s;
    #pragma unroll
    for (int j = 0; j < 8; ++j) {
      *(unsigned*)&lph[p][q4 * 16 + 2 * j] = (unsigned)hb[2*j] | ((unsigned)hb[2*j+1] << 16);
      *(unsigned*)&lpl[p][q4 * 16 + 2 * j] = (unsigned)lb[2*j] | ((unsigned)lb[2*j+1] << 16);
    }
  }
  // prefetch chunk 0 (linear f4 copy, 16 VGPRs held — R7 spill lesson)
  float4 pf[4];
  #pragma unroll
  for (int j = 0; j < 4; ++j) pf[j] = cbf[tid + 256 * j];
  __syncthreads();
  if (tid < 64)
    s_sx[tid] = ((s_part[0][tid] + s_part[1][tid]) + s_part[2][tid]) + s_part[3][tid];
  __syncthreads();

  int w = tid >> 6, l = tid & 63;
  int c16 = l & 15, q = l >> 4;

  // A-frags (R8 layout): lane holds A[m=c16][k=q*8+j]; octet q (dims 0-31), 32+q
  bf16x8 afh0, afh1, afl0, afl1;
  {
    int pt = w * 16 + c16;
    afh0 = *(const bf16x8*)&lph[pt][q * 8];
    afh1 = *(const bf16x8*)&lph[pt][32 + q * 8];
    afl0 = *(const bf16x8*)&lpl[pt][q * 8];
    afl1 = *(const bf16x8*)&lpl[pt][32 + q * 8];
  }
  // C/D 16x16: col=lane&15 (code), row=q*4+r (pt)
  float sx[4];
  #pragma unroll
  for (int r = 0; r < 4; ++r) sx[r] = s_sx[w * 16 + q * 4 + r];

  float best[4]; int bidx[4];
  #pragma unroll
  for (int r = 0; r < 4; ++r) { best[r] = 3.4e38f; bidx[r] = 0; }

  for (int ch = 0; ch < 16; ++ch) {
    __syncthreads();                       // readers of previous chunk done
    #pragma unroll
    for (int j = 0; j < 4; ++j)            // linear b128 store, lane-linear: conflict-free
      *(float4*)&lcf[(tid + 256 * j) * 8] = pf[j];
    if (ch < 15) {                         // prefetch next chunk during MFMAs
      #pragma unroll
      for (int j = 0; j < 4; ++j)
        pf[j] = cbf[(ch + 1) * 1024 + tid + 256 * j];
    }
    __builtin_amdgcn_s_waitcnt(0xc07f);    // lgkmcnt(0) only: ds_writes visible,
    __builtin_amdgcn_s_barrier();          // prefetch loads stay in flight

    f32x4 acc[4];
    #pragma unroll
    for (int nt = 0; nt < 4; ++nt) acc[nt] = (f32x4){0.f, 0.f, 0.f, 0.f};
    #pragma unroll
    for (int nt = 0; nt < 4; ++nt) {       // B frags lane-linear b128: conflict-free
      bf16x8 bh0 = *(const bf16x8*)&lcf[(nt * 128 + l) * 8];
      bf16x8 bh1 = *(const bf16x8*)&lcf[(nt * 128 + 64 + l) * 8];
      bf16x8 bl0 = *(const bf16x8*)&lcf[(512 + nt * 128 + l) * 8];
      bf16x8 bl1 = *(const bf16x8*)&lcf[(512 + nt * 128 + 64 + l) * 8];
      // R8's exact chain order per acc (bit-exact lineage): hh0,hl0,lh0,hh1,hl1,lh1
      acc[nt] = __builtin_amdgcn_mfma_f32_16x16x32_bf16(afh0, bh0, acc[nt], 0, 0, 0);
      acc[nt] = __builtin_amdgcn_mfma_f32_16x16x32_bf16(afh0, bl0, acc[nt], 0, 0, 0);
      acc[nt] = __builtin_amdgcn_mfma_f32_16x16x32_bf16(afl0, bh0, acc[nt], 0, 0, 0);
      acc[nt] = __builtin_amdgcn_mfma_f32_16x16x32_bf16(afh1, bh1, acc[nt], 0, 0, 0);
      acc[nt] = __builtin_amdgcn_mfma_f32_16x16x32_bf16(afh1, bl1, acc[nt], 0, 0, 0);
      acc[nt] = __builtin_amdgcn_mfma_f32_16x16x32_bf16(afl1, bh1, acc[nt], 0, 0, 0);
    }
    // fold (nt asc, ch asc, strict < -> first-min, same as R8)
    #pragma unroll
    for (int nt = 0; nt < 4; ++nt) {
      int kk = ch * 64 + nt * 16 + c16;
      float cnv = s_cn[kk];
      #pragma unroll
      for (int r = 0; r < 4; ++r) {
        float dist = (sx[r] + cnv) - 2.0f * acc[nt][r];
        if (dist < best[r]) { best[r] = dist; bidx[r] = kk; }
      }
    }
  }

  // cross-c16 argmin (16-lane groups; packed u64, tie -> lower idx)
  #pragma unroll
  for (int r = 0; r < 4; ++r) {
    unsigned long long pk =
        ((unsigned long long)__float_as_uint(best[r]) << 32) | (unsigned)bidx[r];
    #pragma unroll
    for (int m = 1; m < 16; m <<= 1) {
      unsigned long long o = __shfl_xor(pk, m, 64);
      pk = (o < pk) ? o : pk;
    }
    if (c16 == 0) {
      int bd = (int)(pk & 0xffffffffull);
      s_bd[w * 16 + q * 4 + r] = bd;
      atomicAdd(&hist[bd], 1);
    }
  }
  __syncthreads();

  // fused fin: gather code row, straight-through write (ref rounding), mse
  float se = 0.f;
  {
    int p = tid & 63, cg = tid >> 6;
    int bd = s_bd[p];
    const float* crow = cb + bd * DIM;
    float* ob = out + b * CHW + hw0 + p;
    #pragma unroll 4
    for (int i = 0; i < 16; ++i) {
      int c = cg * 16 + i;
      float xv   = lpf[c][p];              // bit-exact x copy
      float diff = crow[c] - xv;           // nq - x
      se += diff * diff;                   // (clean_q - flat)^2 == commit mse
      ob[c * HW] = xv + diff;              // x + stop_grad(nq - x)
    }
  }
  float tot = block_sum(se, scratch);
  if (tid == 0) {
    atomicAdd(mseacc, tot);
    __threadfence();                       // release before counter
    int old = atomicAdd(done, 1);
    *s_last = (old == 511);
  }
  __syncthreads();
  if (!*s_last) return;

  // ---------- last block: prep + banded OT dual ascent + scalars (R10-validated) ----
  __threadfence();                         // acquire
  float msetot = *mseacc;
  __syncthreads();                         // before aliasing lph/lpl with OT arrays
  int i0 = tid * 4;
  int sl0 = i0 + 4;

  int4 hi4 = *(const int4*)(hist + i0);
  int  hi[4] = {hi4.x, hi4.y, hi4.z, hi4.w};
  float tj[4], hj[4];
  #pragma unroll
  for (int j = 0; j < 4; ++j) {
    float fi = (float)(i0 + j);
    float zz = (fi - 511.5f) / (1024.0f / 6.0f);
    tj[j] = expf(-0.5f * zz * zz);
    hj[j] = (float)hi[j] * (1.0f / 32768.0f);
  }
  float St = block_sum(tj[0] + tj[1] + tj[2] + tj[3], scratch);
  float tgt[4], ltw[4];
  float l2 = 0.f;
  #pragma unroll
  for (int j = 0; j < 4; ++j) { tgt[j] = fmaxf(tj[j] / fmaxf(St, 1e-12f), 1e-12f); l2 += tgt[j]; }
  float St2 = block_sum(l2, scratch);
  #pragma unroll
  for (int j = 0; j < 4; ++j) { tgt[j] = tgt[j] / St2; ltw[j] = logf(fmaxf(tgt[j], 1e-12f)); }

  float srcw[4];
  float l3 = 0.f;
  #pragma unroll
  for (int j = 0; j < 4; ++j) { srcw[j] = fmaxf(hj[j], 1e-12f); l3 += srcw[j]; }
  float S1 = block_sum(l3, scratch);
  float l4 = 0.f;
  #pragma unroll
  for (int j = 0; j < 4; ++j) { srcw[j] = fmaxf(srcw[j] / S1, 1e-12f); l4 += srcw[j]; }
  float S2 = block_sum(l4, scratch);
  float l5 = 0.f;
  #pragma unroll
  for (int j = 0; j < 4; ++j) { srcw[j] = srcw[j] / S2; l5 += hj[j] * logf(hj[j] + 1e-10f); }
  float ent = block_sum(l5, scratch);

  *(float4*)&s_lt[sl0]  = make_float4(ltw[0], ltw[1], ltw[2], ltw[3]);
  *(float4*)&s_src[sl0] = make_float4(srcw[0], srcw[1], srcw[2], srcw[3]);
  *(float4*)&s_phi[sl0] = make_float4(0.f, 0.f, 0.f, 0.f);
  *(float4*)&s_lse[sl0] = make_float4(0.f, 0.f, 0.f, 0.f);
  if (tid == 0) {                          // pads: inert (validated R3..R10)
    #pragma unroll
    for (int pp = 0; pp < 4; ++pp) {
      s_lt[pp] = -100.f; s_src[pp] = 0.f; s_phi[pp] = 0.f; s_lse[pp] = 0.f;
      s_lt[KCB+4+pp] = -100.f; s_src[KCB+4+pp] = 0.f;
      s_phi[KCB+4+pp] = 0.f;   s_lse[KCB+4+pp] = 0.f;
    }
  }
  __syncthreads();

  float wsr[12];
  #pragma unroll
  for (int m = 0; m < 3; ++m) *(float4*)&wsr[m*4] = *(float4*)&s_src[i0 + m*4];

  float phi[4] = {0.f, 0.f, 0.f, 0.f};
  float lse[4];
  for (int it = 0; it <= 10; ++it) {
    float wl[12], wp[12];
    #pragma unroll
    for (int m = 0; m < 3; ++m) {
      *(float4*)&wl[m*4] = *(float4*)&s_lt[i0 + m*4];
      *(float4*)&wp[m*4] = *(float4*)&s_phi[i0 + m*4];
    }
    #pragma unroll
    for (int j = 0; j < 4; ++j) {
      float mx = -3.0e38f;
      float vv[5];
      #pragma unroll
      for (int qq = 0; qq < 5; ++qq) {
        int m = j + qq + 2;
        float a = wl[m] + (wp[m] - fabsf((float)(qq - 2))) * 20.0f;
        vv[qq] = a;
        mx = fmaxf(mx, a);
      }
      float ssum = 0.f;
      #pragma unroll
      for (int qq = 0; qq < 5; ++qq) ssum += expf(vv[qq] - mx);
      lse[j] = mx + logf(ssum);
    }
    *(float4*)&s_lse[sl0] = make_float4(lse[0], lse[1], lse[2], lse[3]);
    __syncthreads();
    if (it == 10) break;

    float we[12];
    #pragma unroll
    for (int m = 0; m < 3; ++m) *(float4*)&we[m*4] = *(float4*)&s_lse[i0 + m*4];
    #pragma unroll
    for (int j = 0; j < 4; ++j) {
      float basej = ltw[j] + phi[j] * 20.0f;
      float cs = 0.f;
      #pragma unroll
      for (int qq = 0; qq < 5; ++qq) {
        int m = j + qq + 2;
        float a = basej - fabsf((float)(qq - 2)) * 20.0f;
        cs += wsr[m] * expf(a - we[m]);
      }
      phi[j] += 0.5f * (tgt[j] - cs);
    }
    *(float4*)&s_phi[sl0] = make_float4(phi[0], phi[1], phi[2], phi[3]);
    __syncthreads();
  }

  float lo = 0.f;
  #pragma unroll
  for (int j = 0; j < 4; ++j) lo += srcw[j] * (-0.05f * lse[j]) + tgt[j] * phi[j];
  float ot = block_sum(lo, scratch);

  if (tid == 0) {
    out[2097152] = 1.25f * (msetot * (1.0f / 2097152.0f)) + ot;
    out[2097153] = expf(-ent);
  }
}

extern "C" void kernel_launch(void* const* d_in, const int* in_sizes, int n_in,
                              void* d_out, int out_size, void* d_ws, size_t ws_size,
                              hipStream_t stream) {
  const float* x  = (const float*)d_in[0];   // [32,64,32,32]
  const float* cb = (const float*)d_in[1];   // [1024,64]
  float* out = (float*)d_out;                // quantized(2097152) | loss | perplexity

  float4* cbf   = (float4*)d_ws;                       // 256 KB fragment-ordered codes
  float*  cnorm = (float*)((char*)d_ws + 262144);      // 4 KB
  int*    hist  = (int*)((char*)d_ws + 266240);        // 4 KB
  int*    done  = (int*)((char*)d_ws + 270336);        // 4 B
  float*  mseacc= (float*)((char*)d_ws + 270400);      // 4 B

  k_cvt<<<16, 64, 0, stream>>>(cb, cbf, cnorm, hist, done, mseacc);
  k_dist<<<512, 256, 0, stream>>>(x, cb, cbf, cnorm, hist, done, mseacc, out);
}